// Round 16
// baseline (116.888 us; speedup 1.0000x reference)
//
#include <hip/hip_runtime.h>
#include <hip/hip_cooperative_groups.h>
#include <hip/hip_bf16.h>
#include <cstdint>
#include <math.h>

namespace cg = cooperative_groups;

// B=32,S=2048,F=16,H=64,E=256.  BS=65536 rows.
// out[r,e] = sum_f ( mask[r,f] ? mv[f,e] : phi_{f,e}(x[r,f]) ),  phi smooth 1-D.
// Degree-14 Chebyshev per (f,e): out = sum_{f,d} T_d(x_f/6)*c_d[f,e], K=256 GEMM.
// r16: cooperative fusion, DE-RISKED after r15's silent launch failure:
//  - grid 512 (needs only 2 blocks/CU co-resident; LDS 32KB -> 5/CU, VGPR free via LB(256,2))
//  - hipLaunchCooperativeKernel return CHECKED; fallback = proven r12 two-kernel path
//  - blocks 0..127 build Cmat; all blocks prefetch 4 tiles' x/mask under prep; grid sync;
//    4x r12-proven 32-row tile (chain -> swapped MFMA -> LDS-staged full-row nt stores).

#define F_ 16
#define H_ 64
#define E_ 256
#define NT 256
#define BS_TOTAL 65536
#define XSCALE 6.0f
#define PI_F 3.14159265358979f

typedef __attribute__((ext_vector_type(8))) short s16x8;
typedef __attribute__((ext_vector_type(4))) float f32x4;

__device__ __forceinline__ unsigned short f2bf(float f){
  unsigned u = __builtin_bit_cast(unsigned, f);
  u += 0x7FFFu + ((u >> 16) & 1u);
  return (unsigned short)(u >> 16);
}
__device__ __forceinline__ unsigned cvtpk(float a, float b){
  unsigned r; asm("v_cvt_pk_bf16_f32 %0, %1, %2" : "=v"(r) : "v"(a), "v"(b)); return r;
}

// ======== shared device bodies ========

__device__ __forceinline__ void prep_body(int f, int eg, int t,
    const float* __restrict__ W1, const float* __restrict__ b1,
    const float* __restrict__ W2, const float* __restrict__ b2,
    const float* __restrict__ mv, unsigned short* __restrict__ Cmat,
    float (*hs)[H_], float (*ct)[16], float (*ph_s)[17]){
  #pragma unroll
  for (int s = 0; s < 4; ++s){
    int idx = t + s * 256;
    int j = idx >> 6, h = idx & 63;
    float xj = XSCALE * cosf(PI_F * (j + 0.5f) / 16.0f);
    float z = fmaf(xj, W1[f * H_ + h], b1[f * H_ + h]);
    hs[j][h] = 0.5f * z * (1.0f + erff(z * 0.7071067811865475f));
  }
  if (t < 224){
    int d = t >> 4, j = t & 15;
    ct[d][j] = cosf(PI_F * (d + 1) * (j + 0.5f) / 16.0f) * 0.125f;
  }
  __syncthreads();
  {
    const int e_l = t & 31, jp = t >> 5;
    const int e = eg * 32 + e_l;
    const int j0 = jp * 2, j1 = j0 + 1;
    const float4* w2p = (const float4*)(W2 + ((long)f * E_ + e) * H_);
    float b2v = b2[f * E_ + e];
    float p0 = b2v, p1 = b2v;
    #pragma unroll
    for (int hq = 0; hq < 16; ++hq){
      float4 w  = w2p[hq];
      float4 h0 = *(const float4*)&hs[j0][hq * 4];
      float4 h1 = *(const float4*)&hs[j1][hq * 4];
      p0 += w.x * h0.x + w.y * h0.y + w.z * h0.z + w.w * h0.w;
      p1 += w.x * h1.x + w.y * h1.y + w.z * h1.z + w.w * h1.w;
    }
    ph_s[e_l][j0] = p0; ph_s[e_l][j1] = p1;
  }
  __syncthreads();
  if (t < 64){
    const int el = t & 31, g = t >> 5;
    const int ee = eg * 32 + el;
    float ph[16]; float s0 = 0.f;
    #pragma unroll
    for (int j = 0; j < 16; ++j){ ph[j] = ph_s[el][j]; s0 += ph[j]; }
    float c0 = s0 * 0.0625f;
    float vals[8];
    #pragma unroll
    for (int dq = 0; dq < 8; ++dq){
      int dm = g * 8 + dq;
      float v;
      if (dm < 14){
        v = 0.f;
        #pragma unroll
        for (int j = 0; j < 16; ++j) v += ph[j] * ct[dm][j];
      } else if (dm == 14) v = mv[f * E_ + ee] - c0;
      else                 v = c0;
      vals[dq] = v;
    }
    unsigned w[4];
    w[0] = (unsigned)f2bf(vals[0]) | ((unsigned)f2bf(vals[1]) << 16);
    w[1] = (unsigned)f2bf(vals[2]) | ((unsigned)f2bf(vals[3]) << 16);
    w[2] = (unsigned)f2bf(vals[4]) | ((unsigned)f2bf(vals[5]) << 16);
    w[3] = (unsigned)f2bf(vals[6]) | ((unsigned)f2bf(vals[7]) << 16);
    const int kk = g * 4 + (f & 3);
    const int cl = (f >> 2) * 16 + (ee & 15);
    const int eb = ee >> 4;
    long byte = ((long)(kk * 16 + eb) * 64 + cl) * 16;
    *(uint4*)((char*)Cmat + byte) = *(uint4*)w;
  }
}

// one 32-row tile: chain + swapped MFMA into acc
__device__ __forceinline__ void tile_compute(const s16x8* __restrict__ C8,
    const float4 x4[2], unsigned mbits, int wn, int lane, f32x4 acc[2][4]){
  #pragma unroll
  for (int c = 0; c < 4; ++c){
    float t2s[2], T7s[2], T8s[2];
    {
      s16x8 bfr[4];
      #pragma unroll
      for (int n = 0; n < 4; ++n)
        bfr[n] = C8[(c * 16 + wn * 4 + n) * 64 + lane];
      #pragma unroll
      for (int m = 0; m < 2; ++m){
        float xv = ((const float*)&x4[m])[c];
        unsigned masked = (mbits >> (m * 4 + c)) & 1u;
        float uu = xv * (1.0f / XSCALE);
        uu = fminf(1.0f, fmaxf(-1.0f, uu));
        float t2 = uu + uu;
        float T1 = uu;
        float T2 = fmaf(t2, T1, -1.0f);
        float T3 = fmaf(t2, T2, -T1);
        float T4 = fmaf(t2, T3, -T2);
        float T5 = fmaf(t2, T4, -T3);
        float T6 = fmaf(t2, T5, -T4);
        float T7 = fmaf(t2, T6, -T5);
        float T8 = fmaf(t2, T7, -T6);
        t2s[m] = t2; T7s[m] = T7; T8s[m] = T8;
        unsigned z = masked ? 0u : 0xFFFFFFFFu;
        union { unsigned w[4]; s16x8 v; } pk;
        pk.w[0] = cvtpk(T1, T2) & z;  pk.w[1] = cvtpk(T3, T4) & z;
        pk.w[2] = cvtpk(T5, T6) & z;  pk.w[3] = cvtpk(T7, T8) & z;
        #pragma unroll
        for (int n = 0; n < 4; ++n)
          acc[m][n] = __builtin_amdgcn_mfma_f32_16x16x32_bf16(bfr[n], pk.v, acc[m][n], 0, 0, 0);
      }
    }
    {
      s16x8 bfr[4];
      #pragma unroll
      for (int n = 0; n < 4; ++n)
        bfr[n] = C8[((c + 4) * 16 + wn * 4 + n) * 64 + lane];
      #pragma unroll
      for (int m = 0; m < 2; ++m){
        unsigned masked = (mbits >> (m * 4 + c)) & 1u;
        float t2 = t2s[m], T7 = T7s[m], T8 = T8s[m];
        float T9  = fmaf(t2, T8,  -T7);
        float T10 = fmaf(t2, T9,  -T8);
        float T11 = fmaf(t2, T10, -T9);
        float T12 = fmaf(t2, T11, -T10);
        float T13 = fmaf(t2, T12, -T11);
        float T14 = fmaf(t2, T13, -T12);
        unsigned z = masked ? 0u : 0xFFFFFFFFu;
        float mf = masked ? 1.0f : 0.0f;
        union { unsigned w[4]; s16x8 v; } pk;
        pk.w[0] = cvtpk(T9, T10) & z;  pk.w[1] = cvtpk(T11, T12) & z;
        pk.w[2] = cvtpk(T13, T14) & z; pk.w[3] = cvtpk(mf, 1.0f);
        #pragma unroll
        for (int n = 0; n < 4; ++n)
          acc[m][n] = __builtin_amdgcn_mfma_f32_16x16x32_bf16(bfr[n], pk.v, acc[m][n], 0, 0, 0);
      }
    }
  }
}

__device__ __forceinline__ void tile_store(float* __restrict__ osm,
    float* __restrict__ out, const f32x4 acc[2][4],
    int rowBase, int wn, int lane, int rr, int q){
  #pragma unroll
  for (int m = 0; m < 2; ++m){
    #pragma unroll
    for (int n = 0; n < 4; ++n){
      int row = m * 16 + rr;
      int byte = (row * E_ + wn * 64 + n * 16 + q * 4) * 4;
      byte ^= (row & 7) << 4;
      *(f32x4*)((char*)osm + byte) = acc[m][n];
    }
  }
  __syncthreads();
  #pragma unroll
  for (int i = 0; i < 8; ++i){
    int row = wn * 8 + i;
    int byte = (row * E_ + lane * 4) * 4;
    byte ^= (row & 7) << 4;
    f32x4 v = *(const f32x4*)((const char*)osm + byte);
    __builtin_nontemporal_store(v, (f32x4*)&out[(long)(rowBase + row) * E_ + lane * 4]);
  }
}

// ======== cooperative fused kernel (grid 512, 4 tiles/block) ========
__global__ __launch_bounds__(NT, 2)
void ts_fused(const float* __restrict__ x, const int* __restrict__ mask,
              const float* __restrict__ W1, const float* __restrict__ b1,
              const float* __restrict__ W2, const float* __restrict__ b2,
              const float* __restrict__ mv, unsigned short* __restrict__ Cmat,
              float* __restrict__ out){
  __shared__ union {
    struct { float hs[16][H_]; float ct[14][16]; float ph_s[32][17]; } p;
    float osm[32 * E_];
  } sh;

  const int tid = threadIdx.x, lane = tid & 63, wn = tid >> 6;
  const int rr = lane & 15;
  const int q  = lane >> 4;

  // prefetch all 4 tiles' x/mask (hides HBM under prep)
  float4 x4[4][2]; unsigned mbits[4] = {0u, 0u, 0u, 0u};
  #pragma unroll
  for (int t = 0; t < 4; ++t){
    int rowBase = (blockIdx.x * 4 + t) * 32;
    #pragma unroll
    for (int m = 0; m < 2; ++m){
      int r = rowBase + m * 16 + rr;
      x4[t][m] = *(const float4*)&x[r * F_ + q * 4];
      int4 mk = *(const int4*)&mask[r * F_ + q * 4];
      mbits[t] |= (mk.x != 0 ? 1u : 0u) << (m * 4 + 0);
      mbits[t] |= (mk.y != 0 ? 1u : 0u) << (m * 4 + 1);
      mbits[t] |= (mk.z != 0 ? 1u : 0u) << (m * 4 + 2);
      mbits[t] |= (mk.w != 0 ? 1u : 0u) << (m * 4 + 3);
    }
  }

  if (blockIdx.x < 128){
    prep_body(blockIdx.x >> 3, blockIdx.x & 7, tid, W1, b1, W2, b2, mv, Cmat,
              sh.p.hs, sh.p.ct, sh.p.ph_s);
    __threadfence();
  }

  cg::this_grid().sync();

  const s16x8* C8 = (const s16x8*)Cmat;
  #pragma unroll 1
  for (int t = 0; t < 4; ++t){
    const int rowBase = (blockIdx.x * 4 + t) * 32;
    f32x4 acc[2][4] = {};
    tile_compute(C8, x4[t], mbits[t], wn, lane, acc);
    __syncthreads();                         // prev tile's osm reads finished
    tile_store(sh.osm, out, acc, rowBase, wn, lane, rr, q);
  }
}

// ======== fallback (r12-proven two-kernel path) ========
__global__ __launch_bounds__(256)
void prep_cmat(const float* __restrict__ W1, const float* __restrict__ b1,
               const float* __restrict__ W2, const float* __restrict__ b2,
               const float* __restrict__ mv, unsigned short* __restrict__ Cmat){
  __shared__ float hs[16][H_];
  __shared__ float ct[14][16];
  __shared__ float ph_s[32][17];
  prep_body(blockIdx.x >> 3, blockIdx.x & 7, threadIdx.x, W1, b1, W2, b2, mv, Cmat,
            hs, ct, ph_s);
}

__global__ __launch_bounds__(NT, 4)
void ts_main(const float* __restrict__ x, const int* __restrict__ mask,
             const unsigned short* __restrict__ Cmat, float* __restrict__ out){
  __shared__ __align__(16) float osm[32 * E_];
  const int tid = threadIdx.x, lane = tid & 63, wn = tid >> 6;
  const int rr = lane & 15;
  const int q  = lane >> 4;
  const int rowBase = blockIdx.x * 32;

  float4 x4[2]; unsigned mbits = 0;
  #pragma unroll
  for (int m = 0; m < 2; ++m){
    int r = rowBase + m * 16 + rr;
    x4[m] = *(const float4*)&x[r * F_ + q * 4];
    int4 mk = *(const int4*)&mask[r * F_ + q * 4];
    mbits |= (mk.x != 0 ? 1u : 0u) << (m * 4 + 0);
    mbits |= (mk.y != 0 ? 1u : 0u) << (m * 4 + 1);
    mbits |= (mk.z != 0 ? 1u : 0u) << (m * 4 + 2);
    mbits |= (mk.w != 0 ? 1u : 0u) << (m * 4 + 3);
  }
  f32x4 acc[2][4] = {};
  tile_compute((const s16x8*)Cmat, x4, mbits, wn, lane, acc);
  tile_store(osm, out, acc, rowBase, wn, lane, rr, q);
}

extern "C" void kernel_launch(void* const* d_in, const int* in_sizes, int n_in,
                              void* d_out, int out_size, void* d_ws, size_t ws_size,
                              hipStream_t stream) {
  const float* x    = (const float*)d_in[0];
  const int*   mask = (const int*)d_in[1];
  const float* W1   = (const float*)d_in[2];
  const float* b1   = (const float*)d_in[3];
  const float* W2   = (const float*)d_in[4];
  const float* b2   = (const float*)d_in[5];
  const float* mv   = (const float*)d_in[6];
  float* out = (float*)d_out;
  unsigned short* Cmat = (unsigned short*)d_ws;   // 128 KB frag-packed image

  void* args[] = { (void*)&x, (void*)&mask, (void*)&W1, (void*)&b1,
                   (void*)&W2, (void*)&b2, (void*)&mv, (void*)&Cmat, (void*)&out };
  hipError_t err = hipLaunchCooperativeKernel((const void*)ts_fused,
                                              dim3(BS_TOTAL / 128), dim3(NT),
                                              args, 0, stream);
  if (err != hipSuccess){
    // deterministic fallback: proven r12 path
    prep_cmat<<<dim3(128), dim3(256), 0, stream>>>(W1, b1, W2, b2, mv, Cmat);
    ts_main<<<dim3(BS_TOTAL / 32), dim3(NT), 0, stream>>>(x, mask, Cmat, out);
  }
}

// Round 17
// 34.205 us; speedup vs baseline: 3.4173x; 3.4173x over previous
//
#include <hip/hip_runtime.h>
#include <hip/hip_bf16.h>
#include <cstdint>
#include <math.h>

// B=32,S=2048,F=16,H=64,E=256.  BS=65536 rows.
// out[r,e] = sum_f ( mask[r,f] ? mv[f,e] : phi_{f,e}(x[r,f]) ),  phi smooth 1-D.
// Degree-14 Chebyshev per (f,e): out = sum_{f,d} T_d(x_f/6)*c_d[f,e], K=256 GEMM.
// r17: r12 structure (best, 28.1us) with residency opened up: 16KB two-phase LDS
// epilogue (r13-proven) + __launch_bounds__(256,6) -> 6 blocks/CU, 24 waves/CU
// (VGPR budget ~85 >= measured 64; LDS 16KB <= 26KB). Cooperative fusion (r15/r16)
// is dead: grid.sync across XCDs cost ~90us. Two-kernel path retained.
//
// k-bijection: k = kk*32 + q*8 + j ;  c = kk&3, g = kk>>2 ;  f = q*4 + c ; dm = g*8+j.
// A-slot dm=14: m_f (pairs mv-c0), dm=15: 1 (pairs c0).

#define F_ 16
#define H_ 64
#define E_ 256
#define NT 256
#define BS_TOTAL 65536
#define XSCALE 6.0f
#define PI_F 3.14159265358979f

typedef __attribute__((ext_vector_type(8))) short s16x8;
typedef __attribute__((ext_vector_type(4))) float f32x4;

__device__ __forceinline__ unsigned short f2bf(float f){
  unsigned u = __builtin_bit_cast(unsigned, f);
  u += 0x7FFFu + ((u >> 16) & 1u);
  return (unsigned short)(u >> 16);
}
__device__ __forceinline__ unsigned cvtpk(float a, float b){
  unsigned r; asm("v_cvt_pk_bf16_f32 %0, %1, %2" : "=v"(r) : "v"(a), "v"(b)); return r;
}

// ---- prep: 128 blocks = (f, e-group of 32) — unchanged from r7-r14.
__global__ __launch_bounds__(256)
void prep_cmat(const float* __restrict__ W1, const float* __restrict__ b1,
               const float* __restrict__ W2, const float* __restrict__ b2,
               const float* __restrict__ mv, unsigned short* __restrict__ Cmat){
  const int f = blockIdx.x >> 3, eg = blockIdx.x & 7;
  const int t = threadIdx.x;
  __shared__ float hs[16][H_];
  __shared__ float ct[14][16];
  __shared__ float ph_s[32][17];

  #pragma unroll
  for (int s = 0; s < 4; ++s){
    int idx = t + s * 256;
    int j = idx >> 6, h = idx & 63;
    float xj = XSCALE * cosf(PI_F * (j + 0.5f) / 16.0f);
    float z = fmaf(xj, W1[f * H_ + h], b1[f * H_ + h]);
    hs[j][h] = 0.5f * z * (1.0f + erff(z * 0.7071067811865475f));
  }
  if (t < 224){
    int d = t >> 4, j = t & 15;
    ct[d][j] = cosf(PI_F * (d + 1) * (j + 0.5f) / 16.0f) * 0.125f;
  }
  __syncthreads();

  {
    const int e_l = t & 31, jp = t >> 5;
    const int e = eg * 32 + e_l;
    const int j0 = jp * 2, j1 = j0 + 1;
    const float4* w2p = (const float4*)(W2 + ((long)f * E_ + e) * H_);
    float b2v = b2[f * E_ + e];
    float p0 = b2v, p1 = b2v;
    #pragma unroll
    for (int hq = 0; hq < 16; ++hq){
      float4 w  = w2p[hq];
      float4 h0 = *(const float4*)&hs[j0][hq * 4];
      float4 h1 = *(const float4*)&hs[j1][hq * 4];
      p0 += w.x * h0.x + w.y * h0.y + w.z * h0.z + w.w * h0.w;
      p1 += w.x * h1.x + w.y * h1.y + w.z * h1.z + w.w * h1.w;
    }
    ph_s[e_l][j0] = p0; ph_s[e_l][j1] = p1;
  }
  __syncthreads();

  if (t < 64){
    const int el = t & 31, g = t >> 5;
    const int ee = eg * 32 + el;
    float ph[16]; float s0 = 0.f;
    #pragma unroll
    for (int j = 0; j < 16; ++j){ ph[j] = ph_s[el][j]; s0 += ph[j]; }
    float c0 = s0 * 0.0625f;
    float vals[8];
    #pragma unroll
    for (int dq = 0; dq < 8; ++dq){
      int dm = g * 8 + dq;
      float v;
      if (dm < 14){
        v = 0.f;
        #pragma unroll
        for (int j = 0; j < 16; ++j) v += ph[j] * ct[dm][j];
      } else if (dm == 14) v = mv[f * E_ + ee] - c0;
      else                 v = c0;
      vals[dq] = v;
    }
    unsigned w[4];
    w[0] = (unsigned)f2bf(vals[0]) | ((unsigned)f2bf(vals[1]) << 16);
    w[1] = (unsigned)f2bf(vals[2]) | ((unsigned)f2bf(vals[3]) << 16);
    w[2] = (unsigned)f2bf(vals[4]) | ((unsigned)f2bf(vals[5]) << 16);
    w[3] = (unsigned)f2bf(vals[6]) | ((unsigned)f2bf(vals[7]) << 16);
    const int kk = g * 4 + (f & 3);
    const int lane = (f >> 2) * 16 + (ee & 15);
    const int eb = ee >> 4;
    long byte = ((long)(kk * 16 + eb) * 64 + lane) * 16;
    *(uint4*)((char*)Cmat + byte) = *(uint4*)w;
  }
}

// ---- main: 32 rows/block, K=256, A in-register, B from L2, swapped MFMA,
// two-phase 16KB LDS epilogue with full-row nt stores. 6 blocks/CU.
__global__ __launch_bounds__(NT, 6)
void ts_main(const float* __restrict__ x, const int* __restrict__ mask,
             const unsigned short* __restrict__ Cmat, float* __restrict__ out){
  __shared__ __align__(16) float osm[16 * E_];   // 16 KB staging (16-row phase)

  const int tid = threadIdx.x, lane = tid & 63, wn = tid >> 6;
  const int rr = lane & 15;
  const int q  = lane >> 4;
  const int rowBase = blockIdx.x * 32;
  const s16x8* C8 = (const s16x8*)Cmat;

  float4 x4[2]; unsigned mbits = 0;
  #pragma unroll
  for (int m = 0; m < 2; ++m){
    int r = rowBase + m * 16 + rr;
    x4[m] = *(const float4*)&x[r * F_ + q * 4];
    int4 mk = *(const int4*)&mask[r * F_ + q * 4];
    mbits |= (mk.x != 0 ? 1u : 0u) << (m * 4 + 0);
    mbits |= (mk.y != 0 ? 1u : 0u) << (m * 4 + 1);
    mbits |= (mk.z != 0 ? 1u : 0u) << (m * 4 + 2);
    mbits |= (mk.w != 0 ? 1u : 0u) << (m * 4 + 3);
  }

  f32x4 acc[2][4] = {};

  #pragma unroll
  for (int c = 0; c < 4; ++c){
    float t2s[2], T7s[2], T8s[2];

    // ---- phase lo: d 1..8
    {
      s16x8 bfr[4];
      #pragma unroll
      for (int n = 0; n < 4; ++n)
        bfr[n] = C8[(c * 16 + wn * 4 + n) * 64 + lane];
      #pragma unroll
      for (int m = 0; m < 2; ++m){
        float xv = ((const float*)&x4[m])[c];
        unsigned masked = (mbits >> (m * 4 + c)) & 1u;
        float uu = xv * (1.0f / XSCALE);
        uu = fminf(1.0f, fmaxf(-1.0f, uu));
        float t2 = uu + uu;
        float T1 = uu;
        float T2 = fmaf(t2, T1, -1.0f);
        float T3 = fmaf(t2, T2, -T1);
        float T4 = fmaf(t2, T3, -T2);
        float T5 = fmaf(t2, T4, -T3);
        float T6 = fmaf(t2, T5, -T4);
        float T7 = fmaf(t2, T6, -T5);
        float T8 = fmaf(t2, T7, -T6);
        t2s[m] = t2; T7s[m] = T7; T8s[m] = T8;
        unsigned z = masked ? 0u : 0xFFFFFFFFu;
        union { unsigned w[4]; s16x8 v; } pk;
        pk.w[0] = cvtpk(T1, T2) & z;  pk.w[1] = cvtpk(T3, T4) & z;
        pk.w[2] = cvtpk(T5, T6) & z;  pk.w[3] = cvtpk(T7, T8) & z;
        #pragma unroll
        for (int n = 0; n < 4; ++n)
          acc[m][n] = __builtin_amdgcn_mfma_f32_16x16x32_bf16(bfr[n], pk.v, acc[m][n], 0, 0, 0);
      }
    }

    // ---- phase hi: d 9..14 + mask slot + c0 slot
    {
      s16x8 bfr[4];
      #pragma unroll
      for (int n = 0; n < 4; ++n)
        bfr[n] = C8[((c + 4) * 16 + wn * 4 + n) * 64 + lane];
      #pragma unroll
      for (int m = 0; m < 2; ++m){
        unsigned masked = (mbits >> (m * 4 + c)) & 1u;
        float t2 = t2s[m], T7 = T7s[m], T8 = T8s[m];
        float T9  = fmaf(t2, T8,  -T7);
        float T10 = fmaf(t2, T9,  -T8);
        float T11 = fmaf(t2, T10, -T9);
        float T12 = fmaf(t2, T11, -T10);
        float T13 = fmaf(t2, T12, -T11);
        float T14 = fmaf(t2, T13, -T12);
        unsigned z = masked ? 0u : 0xFFFFFFFFu;
        float mf = masked ? 1.0f : 0.0f;
        union { unsigned w[4]; s16x8 v; } pk;
        pk.w[0] = cvtpk(T9, T10) & z;  pk.w[1] = cvtpk(T11, T12) & z;
        pk.w[2] = cvtpk(T13, T14) & z; pk.w[3] = cvtpk(mf, 1.0f);
        #pragma unroll
        for (int n = 0; n < 4; ++n)
          acc[m][n] = __builtin_amdgcn_mfma_f32_16x16x32_bf16(bfr[n], pk.v, acc[m][n], 0, 0, 0);
      }
    }
  }

  // ---- two-phase epilogue: 16 rows per phase through 16 KB LDS, full-row nt stores
  #pragma unroll
  for (int m = 0; m < 2; ++m){
    #pragma unroll
    for (int n = 0; n < 4; ++n){
      int byte = (rr * E_ + wn * 64 + n * 16 + q * 4) * 4;
      byte ^= (rr & 7) << 4;
      *(f32x4*)((char*)osm + byte) = acc[m][n];
    }
    __syncthreads();
    #pragma unroll
    for (int i = 0; i < 4; ++i){
      int row = wn * 4 + i;
      int byte = (row * E_ + lane * 4) * 4;
      byte ^= (row & 7) << 4;
      f32x4 v = *(const f32x4*)((const char*)osm + byte);
      __builtin_nontemporal_store(v, (f32x4*)&out[(long)(rowBase + m * 16 + row) * E_ + lane * 4]);
    }
    __syncthreads();   // osm reused by the second phase
  }
}

extern "C" void kernel_launch(void* const* d_in, const int* in_sizes, int n_in,
                              void* d_out, int out_size, void* d_ws, size_t ws_size,
                              hipStream_t stream) {
  const float* x    = (const float*)d_in[0];
  const int*   mask = (const int*)d_in[1];
  const float* W1   = (const float*)d_in[2];
  const float* b1   = (const float*)d_in[3];
  const float* W2   = (const float*)d_in[4];
  const float* b2   = (const float*)d_in[5];
  const float* mv   = (const float*)d_in[6];
  float* out = (float*)d_out;

  unsigned short* Cmat = (unsigned short*)d_ws;   // 128 KB frag-packed image

  prep_cmat<<<dim3(128), dim3(256), 0, stream>>>(W1, b1, W2, b2, mv, Cmat);
  ts_main<<<dim3(BS_TOTAL / 32), dim3(NT), 0, stream>>>(x, mask, Cmat, out);
}

// Round 18
// 27.948 us; speedup vs baseline: 4.1823x; 1.2239x over previous
//
#include <hip/hip_runtime.h>
#include <hip/hip_bf16.h>
#include <cstdint>
#include <math.h>

// B=32,S=2048,F=16,H=64,E=256.  BS=65536 rows.
// out[r,e] = sum_f ( mask[r,f] ? mv[f,e] : phi_{f,e}(x[r,f]) ),  phi smooth 1-D.
// Degree-14 Chebyshev per (f,e): out = sum_{f,d} T_d(x_f/6)*c_d[f,e], K=256 GEMM.
// r18: REVERT to r12 exactly (best measured: 28.1 us). r17's LB(256,6) squeezed
// VGPR to 40 (below the ~64 live set) and regressed to 34.2; r12's LB(256,4) +
// single-phase 32KB LDS epilogue is the proven optimum of this structure.
//
// k-bijection: k = kk*32 + q*8 + j ;  c = kk&3, g = kk>>2 ;  f = q*4 + c ; dm = g*8+j.
// A-slot dm=14: m_f (pairs mv-c0), dm=15: 1 (pairs c0).

#define F_ 16
#define H_ 64
#define E_ 256
#define NT 256
#define BS_TOTAL 65536
#define XSCALE 6.0f
#define PI_F 3.14159265358979f

typedef __attribute__((ext_vector_type(8))) short s16x8;
typedef __attribute__((ext_vector_type(4))) float f32x4;

__device__ __forceinline__ unsigned short f2bf(float f){
  unsigned u = __builtin_bit_cast(unsigned, f);
  u += 0x7FFFu + ((u >> 16) & 1u);
  return (unsigned short)(u >> 16);
}
__device__ __forceinline__ unsigned cvtpk(float a, float b){
  unsigned r; asm("v_cvt_pk_bf16_f32 %0, %1, %2" : "=v"(r) : "v"(a), "v"(b)); return r;
}

// ---- prep: 128 blocks = (f, e-group of 32).
__global__ __launch_bounds__(256)
void prep_cmat(const float* __restrict__ W1, const float* __restrict__ b1,
               const float* __restrict__ W2, const float* __restrict__ b2,
               const float* __restrict__ mv, unsigned short* __restrict__ Cmat){
  const int f = blockIdx.x >> 3, eg = blockIdx.x & 7;
  const int t = threadIdx.x;
  __shared__ float hs[16][H_];
  __shared__ float ct[14][16];
  __shared__ float ph_s[32][17];

  #pragma unroll
  for (int s = 0; s < 4; ++s){
    int idx = t + s * 256;
    int j = idx >> 6, h = idx & 63;
    float xj = XSCALE * cosf(PI_F * (j + 0.5f) / 16.0f);
    float z = fmaf(xj, W1[f * H_ + h], b1[f * H_ + h]);
    hs[j][h] = 0.5f * z * (1.0f + erff(z * 0.7071067811865475f));
  }
  if (t < 224){
    int d = t >> 4, j = t & 15;
    ct[d][j] = cosf(PI_F * (d + 1) * (j + 0.5f) / 16.0f) * 0.125f;
  }
  __syncthreads();

  {
    const int e_l = t & 31, jp = t >> 5;
    const int e = eg * 32 + e_l;
    const int j0 = jp * 2, j1 = j0 + 1;
    const float4* w2p = (const float4*)(W2 + ((long)f * E_ + e) * H_);
    float b2v = b2[f * E_ + e];
    float p0 = b2v, p1 = b2v;
    #pragma unroll
    for (int hq = 0; hq < 16; ++hq){
      float4 w  = w2p[hq];
      float4 h0 = *(const float4*)&hs[j0][hq * 4];
      float4 h1 = *(const float4*)&hs[j1][hq * 4];
      p0 += w.x * h0.x + w.y * h0.y + w.z * h0.z + w.w * h0.w;
      p1 += w.x * h1.x + w.y * h1.y + w.z * h1.z + w.w * h1.w;
    }
    ph_s[e_l][j0] = p0; ph_s[e_l][j1] = p1;
  }
  __syncthreads();

  if (t < 64){
    const int el = t & 31, g = t >> 5;
    const int ee = eg * 32 + el;
    float ph[16]; float s0 = 0.f;
    #pragma unroll
    for (int j = 0; j < 16; ++j){ ph[j] = ph_s[el][j]; s0 += ph[j]; }
    float c0 = s0 * 0.0625f;
    float vals[8];
    #pragma unroll
    for (int dq = 0; dq < 8; ++dq){
      int dm = g * 8 + dq;
      float v;
      if (dm < 14){
        v = 0.f;
        #pragma unroll
        for (int j = 0; j < 16; ++j) v += ph[j] * ct[dm][j];
      } else if (dm == 14) v = mv[f * E_ + ee] - c0;
      else                 v = c0;
      vals[dq] = v;
    }
    unsigned w[4];
    w[0] = (unsigned)f2bf(vals[0]) | ((unsigned)f2bf(vals[1]) << 16);
    w[1] = (unsigned)f2bf(vals[2]) | ((unsigned)f2bf(vals[3]) << 16);
    w[2] = (unsigned)f2bf(vals[4]) | ((unsigned)f2bf(vals[5]) << 16);
    w[3] = (unsigned)f2bf(vals[6]) | ((unsigned)f2bf(vals[7]) << 16);
    const int kk = g * 4 + (f & 3);
    const int lane = (f >> 2) * 16 + (ee & 15);
    const int eb = ee >> 4;
    long byte = ((long)(kk * 16 + eb) * 64 + lane) * 16;
    *(uint4*)((char*)Cmat + byte) = *(uint4*)w;
  }
}

// ---- main: 32 rows/block, K=256, A in-register, B from L2, swapped MFMA,
// single-phase 32KB LDS epilogue with full-row nt stores (r12-proven).
__global__ __launch_bounds__(NT, 4)
void ts_main(const float* __restrict__ x, const int* __restrict__ mask,
             const unsigned short* __restrict__ Cmat, float* __restrict__ out){
  __shared__ __align__(16) float osm[32 * E_];   // 32 KB staging tile

  const int tid = threadIdx.x, lane = tid & 63, wn = tid >> 6;
  const int rr = lane & 15;
  const int q  = lane >> 4;
  const int rowBase = blockIdx.x * 32;

  float4 x4[2]; unsigned mbits = 0;
  #pragma unroll
  for (int m = 0; m < 2; ++m){
    int r = rowBase + m * 16 + rr;
    x4[m] = *(const float4*)&x[r * F_ + q * 4];
    int4 mk = *(const int4*)&mask[r * F_ + q * 4];
    mbits |= (mk.x != 0 ? 1u : 0u) << (m * 4 + 0);
    mbits |= (mk.y != 0 ? 1u : 0u) << (m * 4 + 1);
    mbits |= (mk.z != 0 ? 1u : 0u) << (m * 4 + 2);
    mbits |= (mk.w != 0 ? 1u : 0u) << (m * 4 + 3);
  }

  const s16x8* C8 = (const s16x8*)Cmat;
  f32x4 acc[2][4] = {};

  #pragma unroll
  for (int c = 0; c < 4; ++c){
    float t2s[2], T7s[2], T8s[2];

    // ---- phase lo: d 1..8
    {
      s16x8 bfr[4];
      #pragma unroll
      for (int n = 0; n < 4; ++n)
        bfr[n] = C8[(c * 16 + wn * 4 + n) * 64 + lane];
      s16x8 afr[2];
      #pragma unroll
      for (int m = 0; m < 2; ++m){
        float xv = ((const float*)&x4[m])[c];
        unsigned masked = (mbits >> (m * 4 + c)) & 1u;
        float uu = xv * (1.0f / XSCALE);
        uu = fminf(1.0f, fmaxf(-1.0f, uu));
        float t2 = uu + uu;
        float T1 = uu;
        float T2 = fmaf(t2, T1, -1.0f);
        float T3 = fmaf(t2, T2, -T1);
        float T4 = fmaf(t2, T3, -T2);
        float T5 = fmaf(t2, T4, -T3);
        float T6 = fmaf(t2, T5, -T4);
        float T7 = fmaf(t2, T6, -T5);
        float T8 = fmaf(t2, T7, -T6);
        t2s[m] = t2; T7s[m] = T7; T8s[m] = T8;
        unsigned z = masked ? 0u : 0xFFFFFFFFu;
        union { unsigned w[4]; s16x8 v; } pk;
        pk.w[0] = cvtpk(T1, T2) & z;  pk.w[1] = cvtpk(T3, T4) & z;
        pk.w[2] = cvtpk(T5, T6) & z;  pk.w[3] = cvtpk(T7, T8) & z;
        afr[m] = pk.v;
      }
      #pragma unroll
      for (int m = 0; m < 2; ++m)
        #pragma unroll
        for (int n = 0; n < 4; ++n)
          acc[m][n] = __builtin_amdgcn_mfma_f32_16x16x32_bf16(bfr[n], afr[m], acc[m][n], 0, 0, 0);
    }

    // ---- phase hi: d 9..14 + mask slot + c0 slot
    {
      s16x8 bfr[4];
      #pragma unroll
      for (int n = 0; n < 4; ++n)
        bfr[n] = C8[((c + 4) * 16 + wn * 4 + n) * 64 + lane];
      s16x8 afr[2];
      #pragma unroll
      for (int m = 0; m < 2; ++m){
        unsigned masked = (mbits >> (m * 4 + c)) & 1u;
        float t2 = t2s[m], T7 = T7s[m], T8 = T8s[m];
        float T9  = fmaf(t2, T8,  -T7);
        float T10 = fmaf(t2, T9,  -T8);
        float T11 = fmaf(t2, T10, -T9);
        float T12 = fmaf(t2, T11, -T10);
        float T13 = fmaf(t2, T12, -T11);
        float T14 = fmaf(t2, T13, -T12);
        unsigned z = masked ? 0u : 0xFFFFFFFFu;
        float mf = masked ? 1.0f : 0.0f;
        union { unsigned w[4]; s16x8 v; } pk;
        pk.w[0] = cvtpk(T9, T10) & z;  pk.w[1] = cvtpk(T11, T12) & z;
        pk.w[2] = cvtpk(T13, T14) & z; pk.w[3] = cvtpk(mf, 1.0f);
        afr[m] = pk.v;
      }
      #pragma unroll
      for (int m = 0; m < 2; ++m)
        #pragma unroll
        for (int n = 0; n < 4; ++n)
          acc[m][n] = __builtin_amdgcn_mfma_f32_16x16x32_bf16(bfr[n], afr[m], acc[m][n], 0, 0, 0);
    }
  }

  // ---- epilogue: stage to LDS (XOR swizzle), then stream full 1KB rows (nt)
  #pragma unroll
  for (int m = 0; m < 2; ++m){
    int row = m * 16 + rr;
    #pragma unroll
    for (int n = 0; n < 4; ++n){
      int byte = (row * E_ + wn * 64 + n * 16 + q * 4) * 4;
      byte ^= (row & 7) << 4;
      *(f32x4*)((char*)osm + byte) = acc[m][n];
    }
  }
  __syncthreads();
  #pragma unroll
  for (int i = 0; i < 8; ++i){
    int row = wn * 8 + i;
    int byte = (row * E_ + lane * 4) * 4;
    byte ^= (row & 7) << 4;
    f32x4 v = *(const f32x4*)((const char*)osm + byte);
    __builtin_nontemporal_store(v, (f32x4*)&out[(long)(rowBase + row) * E_ + lane * 4]);
  }
}

extern "C" void kernel_launch(void* const* d_in, const int* in_sizes, int n_in,
                              void* d_out, int out_size, void* d_ws, size_t ws_size,
                              hipStream_t stream) {
  const float* x    = (const float*)d_in[0];
  const int*   mask = (const int*)d_in[1];
  const float* W1   = (const float*)d_in[2];
  const float* b1   = (const float*)d_in[3];
  const float* W2   = (const float*)d_in[4];
  const float* b2   = (const float*)d_in[5];
  const float* mv   = (const float*)d_in[6];
  float* out = (float*)d_out;

  unsigned short* Cmat = (unsigned short*)d_ws;   // 128 KB frag-packed image

  prep_cmat<<<dim3(128), dim3(256), 0, stream>>>(W1, b1, W2, b2, mv, Cmat);
  ts_main<<<dim3(BS_TOTAL / 32), dim3(NT), 0, stream>>>(x, mask, Cmat, out);
}